// Round 5
// baseline (298.436 us; speedup 1.0000x reference)
//
#include <hip/hip_runtime.h>
#include <hip/hip_bf16.h>
#include <cstdint>
#include <cstddef>

// Shapes (fixed): B=8, S=512, E=H=2048.
#define RTOT 4096      // B*S rows
#define DIM  2048
#define NCAT 6144      // f | c | g column sections
#define NCHUNK 32      // scan chunks
#define TCHUNK 16      // timesteps per chunk

typedef __attribute__((ext_vector_type(4)))  int int4v;
typedef __attribute__((ext_vector_type(16))) int int16v;

__device__ __forceinline__ float fast_sigmoid(float z) {
    return __builtin_amdgcn_rcpf(1.0f + __expf(-z));
}
__device__ __forceinline__ unsigned short f2h(float f) {
    union { _Float16 h; unsigned short u; } v; v.h = (_Float16)f; return v.u;
}
__device__ __forceinline__ float h2f(unsigned short u) {
    union { _Float16 h; unsigned short u; } v; v.u = u; return (float)v.h;
}

// global -> LDS DMA, 16B/lane; dest = wave-uniform base + lane*16.
#define GLDS(gp, lp) __builtin_amdgcn_global_load_lds( \
    (__attribute__((address_space(1))) const void*)(gp), \
    (__attribute__((address_space(3))) void*)(lp), 16, 0, 0)

// LDS rows are 64 B (K=64 in i8). Stored chunk slot = gchunk ^ ((row>>1)&3)
// (0 bank conflicts, verified rounds 2-4). 32x32x32 frag: lane reads rows
// base+(lane&31), k-chunk = ksub*2 + (lane>>5).
__device__ __forceinline__ int4v frag32(const signed char* lds, int R, int ks,
                                        int h5) {
    return *(const int4v*)(lds + R * 64 + (((ks * 2 + h5) ^ ((R >> 1) & 3)) * 16));
}

// ---------------------------------------------------------------------------
// prep_all (unchanged from round 4): weight transpose/cast + act_quant.
__global__ __launch_bounds__(256) void prep_all(
    const float* __restrict__ x, const float* __restrict__ scale,
    const float* __restrict__ Wf, const float* __restrict__ Wc,
    const float* __restrict__ Wg,
    signed char* __restrict__ WcatT, signed char* __restrict__ Wgb,
    signed char* __restrict__ Xq, signed char* __restrict__ Q1,
    signed char* __restrict__ Q2, float* __restrict__ s_arr,
    float* __restrict__ s1_arr)
{
    __shared__ __align__(16) char smem[4224];
    int bid = blockIdx.x;
    int tid = threadIdx.x;
    if (bid < 3072) {
        signed char (*tile)[65] = (signed char(*)[65])smem;
        int j0 = (bid % 96) * 64;
        int k0 = (bid / 96) * 64;
        const float* W = (j0 < 2048) ? Wf : (j0 < 4096) ? Wc : Wg;
        int jb = j0 & 2047;
        int c  = tid & 63;
        int rr = tid >> 6;
#pragma unroll
        for (int p = 0; p < 16; ++p) {
            int kl = p * 4 + rr;
            tile[kl][c] = (signed char)(int)W[(size_t)(k0 + kl) * DIM + jb + c];
        }
        __syncthreads();
#pragma unroll
        for (int p = 0; p < 16; ++p) {
            int jl = p * 4 + rr;
            WcatT[(size_t)(j0 + jl) * DIM + k0 + c] = tile[c][jl];
        }
    } else if (bid < 4096) {
        int idx = (bid - 3072) * 4096 + tid * 16;
#pragma unroll
        for (int p = 0; p < 4; ++p) {
            float4 v = *(const float4*)(Wg + idx + p * 4);
            char4 o;
            o.x = (signed char)(int)v.x; o.y = (signed char)(int)v.y;
            o.z = (signed char)(int)v.z; o.w = (signed char)(int)v.w;
            *(char4*)(Wgb + idx + p * 4) = o;
        }
    } else {
        float* red = (float*)smem;
        float* tot = (float*)(smem + 64);
        int row = bid - 4096;
        const float* xr = x + (size_t)row * DIM + tid * 8;
        const float* sr = scale + tid * 8;
        float4 a0 = *(const float4*)(xr);
        float4 a1 = *(const float4*)(xr + 4);
        float4 c0 = *(const float4*)(sr);
        float4 c1 = *(const float4*)(sr + 4);
        float xs[8] = {a0.x, a0.y, a0.z, a0.w, a1.x, a1.y, a1.z, a1.w};
        float sc[8] = {c0.x, c0.y, c0.z, c0.w, c1.x, c1.y, c1.z, c1.w};
        float sum = 0.f, mx2 = 0.f;
#pragma unroll
        for (int i = 0; i < 8; ++i) {
            sum += xs[i] * xs[i];
            mx2 = fmaxf(mx2, fabsf(xs[i]));
        }
#pragma unroll
        for (int off = 32; off > 0; off >>= 1) {
            sum += __shfl_down(sum, off);
            mx2 = fmaxf(mx2, __shfl_down(mx2, off));
        }
        int lane = tid & 63, wv = tid >> 6;
        if (lane == 0) { red[wv] = sum; red[4 + wv] = mx2; }
        __syncthreads();
        if (tid == 0) {
            tot[0] = red[0] + red[1] + red[2] + red[3];
            tot[1] = fmaxf(fmaxf(red[4], red[5]), fmaxf(red[6], red[7]));
        }
        __syncthreads();
        float rms = 1.0f / sqrtf(tot[0] * (1.0f / 2048.0f) + 1e-5f);
        float y[8]; float mx = 0.f;
#pragma unroll
        for (int i = 0; i < 8; ++i) {
            y[i] = (xs[i] * rms) * sc[i];
            mx = fmaxf(mx, fabsf(y[i]));
        }
#pragma unroll
        for (int off = 32; off > 0; off >>= 1) mx = fmaxf(mx, __shfl_down(mx, off));
        if (lane == 0) red[8 + wv] = mx;
        __syncthreads();
        if (tid == 0)
            tot[2] = fmaxf(fmaxf(red[8], red[9]), fmaxf(red[10], red[11]));
        __syncthreads();
        float s = 127.0f / (tot[2] + 1e-5f);
        s = fminf(fmaxf(s, 0.001f), 1000.0f);
        float s1 = 127.0f / (tot[1] + 1e-5f);
        float inv_s1 = 1.0f / s1;
        if (tid == 0) { s_arr[row] = s; s1_arr[row] = s1; }
        signed char q8[8], q1b[8], q2b[8];
#pragma unroll
        for (int i = 0; i < 8; ++i) {
            float q = fminf(fmaxf(rintf(s * y[i]), -128.f), 127.f);
            q8[i] = (signed char)(int)q;
            float qq1 = fminf(fmaxf(rintf(s1 * xs[i]), -128.f), 127.f);
            q1b[i] = (signed char)(int)qq1;
            float r = xs[i] - qq1 * inv_s1;
            float qq2 = fminf(fmaxf(rintf(s1 * 256.f * r), -128.f), 127.f);
            q2b[i] = (signed char)(int)qq2;
        }
        size_t o = (size_t)row * DIM + tid * 8;
        *(int2*)(Xq + o) = *(int2*)q8;
        *(int2*)(Q1 + o) = *(int2*)q1b;
        *(int2*)(Q2 + o) = *(int2*)q2b;
    }
}

// ---------------------------------------------------------------------------
// gemm_all: 32x32x32 i8 MFMA, fat tiles. fcg: 128x256 block (wave 64x128);
// cg: 64x256 block, two i8 planes (wave 32x128). 3:2 interleave, single
// barrier per 64-K iter, double-buffered LDS (2 x 24 KB).
__global__ __launch_bounds__(256) void gemm_all(
    const signed char* __restrict__ Xq, const signed char* __restrict__ WcatT,
    const signed char* __restrict__ Q1, const signed char* __restrict__ Q2,
    const signed char* __restrict__ Wgb,
    const float* __restrict__ s_arr, const float* __restrict__ s1_arr,
    const float* __restrict__ b_f, const float* __restrict__ b_c,
    const float* __restrict__ b_g,
    unsigned short* __restrict__ FCG,   // (4096 x 6144) fp16
    unsigned short* __restrict__ U,     // cg*x  fp16
    unsigned short* __restrict__ V)     // 1-cg  fp16
{
    __shared__ __align__(16) signed char lds[49152];
    int bid = blockIdx.x;
    int grp = bid / 5, r5 = bid % 5;
    int tid = threadIdx.x;
    int lane = tid & 63, wv = tid >> 6;
    int l31 = lane & 31, h5 = lane >> 5;
    int rA = lane >> 2;
    int gch = ((lane & 3) ^ ((lane >> 3) & 3)) * 16;

    if (r5 < 3) {
        // ---- fcg: 128x256, waves 2x2 (wave tile 64x128) ----
        int fb = grp * 3 + r5;                 // 0..767
        int m0 = (fb / 24) * 128;
        int n0 = (fb % 24) * 256;
        int wm = (wv >> 1) * 64, wn = (wv & 1) * 128;
        const signed char* Ab = Xq + (size_t)m0 * DIM;
        const signed char* Bb = WcatT + (size_t)n0 * DIM;

        int16v acc[2][4] = {};
        // stage tile 0: regions 0-7 = A(128 rows), 8-23 = B(256 rows)
#pragma unroll
        for (int it = 0; it < 6; ++it) {
            int region = wv + it * 4;
            const signed char* g = (region < 8)
                ? Ab + (size_t)(region * 16 + rA) * DIM
                : Bb + (size_t)((region - 8) * 16 + rA) * DIM;
            GLDS(g + gch, lds + region * 1024);
        }
        for (int k6 = 0; k6 < 32; ++k6) {
            const signed char* cur = lds + (k6 & 1) * 24576;
            signed char* nxt = lds + ((k6 + 1) & 1) * 24576;
            __syncthreads();
            if (k6 + 1 < 32) {
                int kt = (k6 + 1) * 64;
#pragma unroll
                for (int it = 0; it < 6; ++it) {
                    int region = wv + it * 4;
                    const signed char* g = (region < 8)
                        ? Ab + (size_t)(region * 16 + rA) * DIM
                        : Bb + (size_t)((region - 8) * 16 + rA) * DIM;
                    GLDS(g + kt + gch, nxt + region * 1024);
                }
            }
#pragma unroll
            for (int ks = 0; ks < 2; ++ks) {
                int4v af[2], bb[4];
#pragma unroll
                for (int mi = 0; mi < 2; ++mi)
                    af[mi] = frag32(cur, wm + mi * 32 + l31, ks, h5);
#pragma unroll
                for (int nj = 0; nj < 4; ++nj)
                    bb[nj] = frag32(cur + 8192, wn + nj * 32 + l31, ks, h5);
#pragma unroll
                for (int mi = 0; mi < 2; ++mi)
#pragma unroll
                    for (int nj = 0; nj < 4; ++nj)
                        acc[mi][nj] = __builtin_amdgcn_mfma_i32_32x32x32_i8(
                            af[mi], bb[nj], acc[mi][nj], 0, 0, 0);
            }
        }
        // epilogue: C/D 32x32: row=(r&3)+8*(r>>2)+4*h5, col=l31
#pragma unroll
        for (int mi = 0; mi < 2; ++mi) {
            float rinv[16];
#pragma unroll
            for (int r = 0; r < 16; ++r) {
                int grow = m0 + wm + mi * 32 + (r & 3) + 8 * (r >> 2) + 4 * h5;
                rinv[r] = __builtin_amdgcn_rcpf(s_arr[grow]);
            }
#pragma unroll
            for (int nj = 0; nj < 4; ++nj) {
                int gcol = n0 + wn + nj * 32 + l31;
                int sec = gcol >> 11;
                int jj = gcol & 2047;
                float bias = (sec == 0) ? b_f[jj] : (sec == 1) ? b_c[jj] : b_g[jj];
#pragma unroll
                for (int r = 0; r < 16; ++r) {
                    int grow = m0 + wm + mi * 32 + (r & 3) + 8 * (r >> 2) + 4 * h5;
                    float z = fmaf((float)acc[mi][nj][r], rinv[r], bias);
                    float sg = fast_sigmoid(z);
                    FCG[(size_t)grow * NCAT + gcol] = f2h((sec == 1) ? z * sg : sg);
                }
            }
        }
    } else {
        // ---- cg: 64x256, waves 2x2 (wave tile 32x128), two i8 planes ----
        int cb = grp * 2 + (r5 - 3);           // 0..511
        int m0 = (cb >> 3) * 64;
        int n0 = (cb & 7) * 256;
        int wm = (wv >> 1) * 32, wn = (wv & 1) * 128;
        const signed char* A1b = Q1 + (size_t)m0 * DIM;
        const signed char* A2b = Q2 + (size_t)m0 * DIM;
        const signed char* Bb  = Wgb + (size_t)n0 * DIM;

        int16v acc1[4] = {};
        int16v acc2[4] = {};
        // regions 0-3 = A1(64 rows), 4-7 = A2, 8-23 = B(256 rows)
#pragma unroll
        for (int it = 0; it < 6; ++it) {
            int region = wv + it * 4;
            const signed char* g = (region < 4)
                ? A1b + (size_t)(region * 16 + rA) * DIM
                : (region < 8)
                    ? A2b + (size_t)((region - 4) * 16 + rA) * DIM
                    : Bb + (size_t)((region - 8) * 16 + rA) * DIM;
            GLDS(g + gch, lds + region * 1024);
        }
        for (int k6 = 0; k6 < 32; ++k6) {
            const signed char* cur = lds + (k6 & 1) * 24576;
            signed char* nxt = lds + ((k6 + 1) & 1) * 24576;
            __syncthreads();
            if (k6 + 1 < 32) {
                int kt = (k6 + 1) * 64;
#pragma unroll
                for (int it = 0; it < 6; ++it) {
                    int region = wv + it * 4;
                    const signed char* g = (region < 4)
                        ? A1b + (size_t)(region * 16 + rA) * DIM
                        : (region < 8)
                            ? A2b + (size_t)((region - 4) * 16 + rA) * DIM
                            : Bb + (size_t)((region - 8) * 16 + rA) * DIM;
                    GLDS(g + kt + gch, nxt + region * 1024);
                }
            }
#pragma unroll
            for (int ks = 0; ks < 2; ++ks) {
                int4v a1 = frag32(cur, wm + l31, ks, h5);
                int4v a2 = frag32(cur + 4096, wm + l31, ks, h5);
                int4v bb[4];
#pragma unroll
                for (int nj = 0; nj < 4; ++nj)
                    bb[nj] = frag32(cur + 8192, wn + nj * 32 + l31, ks, h5);
#pragma unroll
                for (int nj = 0; nj < 4; ++nj) {
                    acc1[nj] = __builtin_amdgcn_mfma_i32_32x32x32_i8(
                        a1, bb[nj], acc1[nj], 0, 0, 0);
                    acc2[nj] = __builtin_amdgcn_mfma_i32_32x32x32_i8(
                        a2, bb[nj], acc2[nj], 0, 0, 0);
                }
            }
        }
        float rinv[16];
#pragma unroll
        for (int r = 0; r < 16; ++r) {
            int grow = m0 + wm + (r & 3) + 8 * (r >> 2) + 4 * h5;
            rinv[r] = __builtin_amdgcn_rcpf(s1_arr[grow]);
        }
#pragma unroll
        for (int nj = 0; nj < 4; ++nj) {
            int gcol = n0 + wn + nj * 32 + l31;
#pragma unroll
            for (int r = 0; r < 16; ++r) {
                int grow = m0 + wm + (r & 3) + 8 * (r >> 2) + 4 * h5;
                size_t go = (size_t)grow * DIM + gcol;
                float zs = (float)acc1[nj][r] + (float)acc2[nj][r] * (1.f / 256.f);
                float cg = fast_sigmoid(zs * rinv[r]);
                float xv = ((float)Q1[go] + (float)Q2[go] * (1.f / 256.f)) * rinv[r];
                U[go] = f2h(cg * xv);
                V[go] = f2h(1.f - cg);
            }
        }
    }
}

// ---------------------------------------------------------------------------
// Scan phase 1: 2 chains/thread, 16-step chunks.
__global__ __launch_bounds__(256) void scan_partial(
    const unsigned short* __restrict__ FCG, const unsigned short* __restrict__ U,
    const unsigned short* __restrict__ V, float4* __restrict__ PQ4)
{
    int tp = blockIdx.x * 256 + threadIdx.x;   // pair 0..1023
    int c = blockIdx.y;
    int b = blockIdx.z;
    int h0 = tp * 2;
    size_t r0 = (size_t)(b * 512 + c * TCHUNK);
    const unsigned short* fp = FCG + r0 * NCAT + h0;
    const unsigned short* up = U + r0 * DIM + h0;
    const unsigned short* vp = V + r0 * DIM + h0;
    float P0 = 1.f, Q0 = 0.f, P1 = 1.f, Q1v = 0.f;
#pragma unroll 4
    for (int t = 0; t < TCHUNK; ++t) {
        unsigned fw = *(const unsigned*)(fp);
        unsigned cw = *(const unsigned*)(fp + 2048);
        unsigned uw = *(const unsigned*)(up);
        unsigned vw = *(const unsigned*)(vp);
        float f0 = h2f(fw & 0xffff), f1 = h2f(fw >> 16);
        float c0 = h2f(cw & 0xffff), c1 = h2f(cw >> 16);
        float u0 = h2f(uw & 0xffff), u1 = h2f(uw >> 16);
        float v0 = h2f(vw & 0xffff), v1 = h2f(vw >> 16);
        float A0 = v0 * f0, A1 = v1 * f1;
        float B0 = fmaf(v0 * (1.f - f0), c0, u0);
        float B1 = fmaf(v1 * (1.f - f1), c1, u1);
        P0 = A0 * P0; Q0 = fmaf(A0, Q0, B0);
        P1 = A1 * P1; Q1v = fmaf(A1, Q1v, B1);
        fp += NCAT; up += DIM; vp += DIM;
    }
    float4 o; o.x = P0; o.y = Q0; o.z = P1; o.w = Q1v;
    PQ4[(size_t)c * 8192 + b * 1024 + tp] = o;
}

// Scan phase 2: recombine summaries for chunk-entry h, replay, emit o_t.
__global__ __launch_bounds__(256) void scan_final(
    const unsigned short* __restrict__ FCG, const unsigned short* __restrict__ U,
    const unsigned short* __restrict__ V, const float4* __restrict__ PQ4,
    float* __restrict__ out)
{
    int tp = blockIdx.x * 256 + threadIdx.x;
    int c = blockIdx.y;
    int b = blockIdx.z;
    int h0 = tp * 2;
    float h0s = 0.f, h1s = 0.f;
    for (int cc = 0; cc < c; ++cc) {
        float4 pq = PQ4[(size_t)cc * 8192 + b * 1024 + tp];
        h0s = fmaf(pq.x, h0s, pq.y);
        h1s = fmaf(pq.z, h1s, pq.w);
    }
    size_t r0 = (size_t)(b * 512 + c * TCHUNK);
    const unsigned short* fp = FCG + r0 * NCAT + h0;
    const unsigned short* up = U + r0 * DIM + h0;
    const unsigned short* vp = V + r0 * DIM + h0;
    float* op = out + r0 * DIM + h0;
#pragma unroll 4
    for (int t = 0; t < TCHUNK; ++t) {
        unsigned fw = *(const unsigned*)(fp);
        unsigned cw = *(const unsigned*)(fp + 2048);
        unsigned gw = *(const unsigned*)(fp + 4096);
        unsigned uw = *(const unsigned*)(up);
        unsigned vw = *(const unsigned*)(vp);
        float f0 = h2f(fw & 0xffff), f1 = h2f(fw >> 16);
        float c0 = h2f(cw & 0xffff), c1 = h2f(cw >> 16);
        float g0 = h2f(gw & 0xffff), g1 = h2f(gw >> 16);
        float u0 = h2f(uw & 0xffff), u1 = h2f(uw >> 16);
        float v0 = h2f(vw & 0xffff), v1 = h2f(vw >> 16);
        float hn0 = f0 * h0s + (1.f - f0) * c0;
        float hn1 = f1 * h1s + (1.f - f1) * c1;
        float2 ov; ov.x = g0 * hn0; ov.y = g1 * hn1;
        *(float2*)op = ov;
        h0s = fmaf(v0, hn0, u0);
        h1s = fmaf(v1, hn1, u1);
        fp += NCAT; up += DIM; vp += DIM; op += DIM;
    }
}

// ---------------------------------------------------------------------------
extern "C" void kernel_launch(void* const* d_in, const int* in_sizes, int n_in,
                              void* d_out, int out_size, void* d_ws, size_t ws_size,
                              hipStream_t stream) {
    const float* x     = (const float*)d_in[0];
    const float* rmssc = (const float*)d_in[1];
    const float* W_f   = (const float*)d_in[2];
    const float* W_c   = (const float*)d_in[3];
    const float* W_g   = (const float*)d_in[4];
    const float* b_f   = (const float*)d_in[5];
    const float* b_c   = (const float*)d_in[6];
    const float* b_g   = (const float*)d_in[7];
    float* out = (float*)d_out;

    char* ws = (char*)d_ws;
    size_t off = 0;
    auto alloc = [&](size_t bytes) -> void* {
        void* p = ws + off;
        off += (bytes + 255) & ~(size_t)255;
        return p;
    };
    signed char* WcatT = (signed char*)alloc((size_t)NCAT * DIM);
    signed char* Wgb   = (signed char*)alloc((size_t)DIM * DIM);
    signed char* Xq    = (signed char*)alloc((size_t)RTOT * DIM);
    signed char* Q1    = (signed char*)alloc((size_t)RTOT * DIM);
    signed char* Q2    = (signed char*)alloc((size_t)RTOT * DIM);
    float* s_arr       = (float*)alloc((size_t)RTOT * 4);
    float* s1_arr      = (float*)alloc((size_t)RTOT * 4);
    unsigned short* FCG = (unsigned short*)alloc((size_t)RTOT * NCAT * 2);
    unsigned short* U   = (unsigned short*)alloc((size_t)RTOT * DIM * 2);
    unsigned short* V   = (unsigned short*)alloc((size_t)RTOT * DIM * 2);
    float4* PQ4        = (float4*)alloc((size_t)NCHUNK * 8192 * 16);

    hipLaunchKernelGGL(prep_all, dim3(8192), dim3(256), 0, stream,
                       x, rmssc, W_f, W_c, W_g, WcatT, Wgb, Xq, Q1, Q2,
                       s_arr, s1_arr);
    hipLaunchKernelGGL(gemm_all, dim3(1280), dim3(256), 0, stream,
                       Xq, WcatT, Q1, Q2, Wgb, s_arr, s1_arr,
                       b_f, b_c, b_g, FCG, U, V);
    hipLaunchKernelGGL(scan_partial, dim3(4, NCHUNK, 8), dim3(256), 0, stream,
                       FCG, U, V, PQ4);
    hipLaunchKernelGGL(scan_final, dim3(4, NCHUNK, 8), dim3(256), 0, stream,
                       FCG, U, V, PQ4, out);
}